// Round 1
// baseline (95.757 us; speedup 1.0000x reference)
//
#include <hip/hip_runtime.h>
#include <math.h>

#define BB 1024
#define DD 64
#define NPIX (1024*3*64*64)

__device__ __constant__ const float LOG2PI_F = 1.8378770664093453f;
__device__ __constant__ const float LOG2E_F  = 1.4426950408889634f;

#define INV_M  (1.0f/1023.0f)
#define INV_N  (1.0f/50000.0f)
#define STRATF ((float)((50000.0-1023.0)/(50000.0*1023.0)))
#define NEGBIG (-3.0e38f)

// ws layout (float offsets)
#define WS_RP    0         // 2048 recon partials
#define WS_LQC   2048      // 1024
#define WS_LPZ   3072      // 1024
#define WS_LQZ   4096      // 1024
#define WS_LPR   5120      // 1024
#define WS_Z     6144      // 65536
#define WS_WH2   71680     // 65536
#define WS_C02   137216    // 65536
#define WS_QZP   202752    // 8*1024*2 = 16384
#define WS_SEP   219136    // 4*1024*64 = 262144
// total = 481280 floats = 1.93 MB

// ---------------- recon MSE ----------------
__global__ __launch_bounds__(256) void k_recon(const float4* __restrict__ rx,
                                               const float4* __restrict__ x,
                                               float* __restrict__ ws) {
    int gid = blockIdx.x * 256 + threadIdx.x;
    const int n4 = NPIX / 4, stride = 2048 * 256;
    float acc = 0.f;
    for (int idx = gid; idx < n4; idx += stride) {
        float4 a = rx[idx], b = x[idx];
        float d0 = a.x - b.x, d1 = a.y - b.y, d2 = a.z - b.z, d3 = a.w - b.w;
        acc = fmaf(d0, d0, acc); acc = fmaf(d1, d1, acc);
        acc = fmaf(d2, d2, acc); acc = fmaf(d3, d3, acc);
    }
    __shared__ float red[256];
    red[threadIdx.x] = acc; __syncthreads();
    for (int o = 128; o > 0; o >>= 1) {
        if (threadIdx.x < o) red[threadIdx.x] += red[threadIdx.x + o];
        __syncthreads();
    }
    if (threadIdx.x == 0) ws[WS_RP + blockIdx.x] = red[0];
}

// ---------------- prep: z, wh2, c02 (base-2 premultiplied) ----------------
__global__ __launch_bounds__(256) void k_prep(const float* __restrict__ mu,
                                              const float* __restrict__ logvar,
                                              const float* __restrict__ noise,
                                              float* __restrict__ ws) {
    int idx = blockIdx.x * 256 + threadIdx.x;
    if (idx >= BB * DD) return;
    float lv = logvar[idx], m = mu[idx], n = noise[idx];
    float z = fmaf(n, exp2f(0.5f * LOG2E_F * lv), m);       // mu + noise*e^{lv/2}
    ws[WS_Z   + idx] = z;
    ws[WS_WH2 + idx] = -0.5f * LOG2E_F * exp2f(-LOG2E_F * lv);  // -0.5 e^{-lv} * log2e
    ws[WS_C02 + idx] = -0.5f * LOG2E_F * (LOG2PI_F + lv);       // -0.5(log2pi+lv)*log2e
}

// ---------------- per-row: log_q_zCx and log_pz ----------------
__global__ __launch_bounds__(256) void k_rowred(const float* __restrict__ logvar,
                                                const float* __restrict__ noise,
                                                float* __restrict__ ws) {
    int t = threadIdx.x, lane = t & 63, wv = t >> 6;
    int r = blockIdx.x * 4 + wv;
    int idx = r * DD + lane;
    float lv = logvar[idx], n = noise[idx], z = ws[WS_Z + idx];
    float a = -0.5f * (LOG2PI_F + lv + n * n);   // log q(z|x) elementwise (nat)
    float b = -0.5f * (LOG2PI_F + z * z);        // log p(z) elementwise (nat)
    for (int off = 32; off > 0; off >>= 1) {
        a += __shfl_xor(a, off, 64);
        b += __shfl_xor(b, off, 64);
    }
    if (lane == 0) { ws[WS_LQC + r] = a; ws[WS_LPZ + r] = b; }
}

// ---------------- S[i,j] row LSE partials (for log_qz) ----------------
// block: 16 i x 128 j; grid 64*8
__global__ __launch_bounds__(256) void k_srow(const float* __restrict__ mu,
                                              float* __restrict__ ws) {
    __shared__ float zs[16][66], ms[16][66], wsh[16][66], cs[16][66];
    __shared__ float mred[16][17], sred[16][17];
    int t = threadIdx.x, tx = t & 15, ty = t >> 4;
    int ic = blockIdx.x >> 3, jc = blockIdx.x & 7;
    int i0 = ic * 16, j0 = jc * 128;

    float l2invm  = -log2f(1023.0f);
    float l2invn  = -log2f(50000.0f);
    float l2strat = log2f(STRATF);

    for (int e = 0; e < 4; e++) {
        int lin = e * 256 + t; int r = lin >> 6, dd = lin & 63;
        zs[r][dd] = ws[WS_Z + (i0 + r) * DD + dd];
    }
    float m = NEGBIG, sum = 0.f;
    for (int jt = 0; jt < 8; ++jt) {
        __syncthreads();
        int jr0 = j0 + jt * 16;
        for (int e = 0; e < 4; e++) {
            int lin = e * 256 + t; int r = lin >> 6, dd = lin & 63;
            int g = (jr0 + r) * DD + dd;
            ms[r][dd]  = mu[g];
            wsh[r][dd] = ws[WS_WH2 + g];
            cs[r][dd]  = ws[WS_C02 + g];
        }
        __syncthreads();
        float s = 0.f;
        const float* zp = &zs[ty][0];
        const float* mp = &ms[tx][0];
        const float* wp = &wsh[tx][0];
        const float* cp = &cs[tx][0];
        #pragma unroll
        for (int dd = 0; dd < DD; dd += 2) {
            float2 zz = *(const float2*)(zp + dd);
            float2 mm = *(const float2*)(mp + dd);
            float2 ww = *(const float2*)(wp + dd);
            float2 cc = *(const float2*)(cp + dd);
            float t1 = zz.x - mm.x; s += cc.x; s = fmaf(ww.x * t1, t1, s);
            float t2 = zz.y - mm.y; s += cc.y; s = fmaf(ww.y * t2, t2, s);
        }
        int i = i0 + ty, j = jr0 + tx;
        float lw = (j == 1) ? l2strat
                 : (i == j) ? l2invn
                 : (i == BB - 2 && j == 0) ? l2strat
                 : l2invm;
        float v = s + 64.f * lw;       // base-2 log of summand
        float nm = fmaxf(m, v);
        sum = sum * exp2f(m - nm) + exp2f(v - nm);
        m = nm;
    }
    mred[ty][tx] = m; sred[ty][tx] = sum;
    __syncthreads();
    if (tx == 0) {
        float M = NEGBIG;
        for (int xx = 0; xx < 16; xx++) M = fmaxf(M, mred[ty][xx]);
        float S = 0.f;
        for (int xx = 0; xx < 16; xx++) S += sred[ty][xx] * exp2f(mred[ty][xx] - M);
        int i = i0 + ty;
        ws[WS_QZP + (jc * BB + i) * 2]     = M;
        ws[WS_QZP + (jc * BB + i) * 2 + 1] = S;
    }
}

// combine 8 j-chunk partials -> log_qz (natural log)
__global__ __launch_bounds__(256) void k_lqz(float* __restrict__ ws) {
    int i = blockIdx.x * 256 + threadIdx.x;
    if (i >= BB) return;
    float M = NEGBIG;
    for (int c = 0; c < 8; c++) M = fmaxf(M, ws[WS_QZP + (c * BB + i) * 2]);
    float S = 0.f;
    for (int c = 0; c < 8; c++)
        S += ws[WS_QZP + (c * BB + i) * 2 + 1] * exp2f(ws[WS_QZP + (c * BB + i) * 2] - M);
    ws[WS_LQZ + i] = (M + log2f(S)) * (1.0f / LOG2E_F);
}

// ---------------- per-(i,d) sum of exp2(u) over j (unweighted) ----------------
// grid (128 i-chunks, 4 j-chunks), block 256: d = t&63, wave w covers 64 j's
__global__ __launch_bounds__(256) void k_sed(const float* __restrict__ mu,
                                             float* __restrict__ ws) {
    __shared__ float sacc[4][8][64];
    int t = threadIdx.x, d = t & 63, w = t >> 6;
    int i0 = blockIdx.x * 8, jc = blockIdx.y;
    float zr[8];
    #pragma unroll
    for (int k = 0; k < 8; k++) zr[k] = ws[WS_Z + (i0 + k) * DD + d];
    float se[8] = {0.f, 0.f, 0.f, 0.f, 0.f, 0.f, 0.f, 0.f};
    int jbase = jc * 256 + w * 64;
    for (int jj = 0; jj < 64; ++jj) {
        int g = (jbase + jj) * DD + d;
        float mm = mu[g], wh = ws[WS_WH2 + g], cc = ws[WS_C02 + g];
        #pragma unroll
        for (int k = 0; k < 8; k++) {
            float tt = zr[k] - mm;
            float u = fmaf(wh * tt, tt, cc);
            se[k] += exp2f(u);
        }
    }
    #pragma unroll
    for (int k = 0; k < 8; k++) sacc[w][k][d] = se[k];
    __syncthreads();
    int k0 = w * 2;
    for (int k = k0; k < k0 + 2; k++) {
        float tot = sacc[0][k][d] + sacc[1][k][d] + sacc[2][k][d] + sacc[3][k][d];
        ws[WS_SEP + (jc * BB + i0 + k) * DD + d] = tot;
    }
}

// epilogue: weights + special-j corrections, log, sum over d -> log_prod_qzi
__global__ __launch_bounds__(256) void k_lpr(const float* __restrict__ mu,
                                             float* __restrict__ ws) {
    int t = threadIdx.x, d = t & 63, w = t >> 6;
    int i = blockIdx.x * 4 + w;
    float se = 0.f;
    for (int c = 0; c < 4; c++) se += ws[WS_SEP + (c * BB + i) * DD + d];
    float zz = ws[WS_Z + i * DD + d];
    auto eat = [&](int j) -> float {
        int g = j * DD + d;
        float mm = mu[g];
        float tt = zz - mm;
        return exp2f(fmaf(ws[WS_WH2 + g] * tt, tt, ws[WS_C02 + g]));
    };
    float sid = INV_M * se;
    if (i != 1)      sid += (INV_N  - INV_M) * eat(i);   // diagonal (unless col-1 overwrote it)
    sid += (STRATF - INV_M) * eat(1);                    // column 1 = strat (all rows)
    if (i == BB - 2) sid += (STRATF - INV_M) * eat(0);   // W[B-2,0] = strat
    float l = log2f(sid);
    for (int off = 32; off > 0; off >>= 1) l += __shfl_xor(l, off, 64);
    if (d == 0) ws[WS_LPR + i] = l * (1.0f / LOG2E_F);
}

// ---------------- final combine ----------------
__global__ __launch_bounds__(256) void k_final(const float* __restrict__ ws,
                                               float* __restrict__ out) {
    int t = threadIdx.x;
    float a0 = 0, a1 = 0, a2 = 0, a3 = 0, a4 = 0;
    for (int idx = t; idx < 2048; idx += 256) a0 += ws[WS_RP + idx];
    for (int idx = t; idx < BB; idx += 256) {
        a1 += ws[WS_LQC + idx];
        a2 += ws[WS_LPZ + idx];
        a3 += ws[WS_LQZ + idx];
        a4 += ws[WS_LPR + idx];
    }
    __shared__ float red[256];
    float vals[5] = {a0, a1, a2, a3, a4};
    float res[5];
    for (int q = 0; q < 5; q++) {
        red[t] = vals[q]; __syncthreads();
        for (int o = 128; o > 0; o >>= 1) {
            if (t < o) red[t] += red[t + o];
            __syncthreads();
        }
        res[q] = red[0]; __syncthreads();
    }
    if (t == 0) {
        float recon = res[0], slqc = res[1], slpz = res[2], slqz = res[3], slpr = res[4];
        // recon + mi + 6*tc + dw_kl = recon + (slqc + 5*slqz - 5*slpr - slpz)/B
        out[0] = recon + (slqc + 5.f * (slqz - slpr) - slpz) * (1.0f / (float)BB);
    }
}

extern "C" void kernel_launch(void* const* d_in, const int* in_sizes, int n_in,
                              void* d_out, int out_size, void* d_ws, size_t ws_size,
                              hipStream_t stream) {
    (void)in_sizes; (void)n_in; (void)out_size; (void)ws_size;
    const float* rx = (const float*)d_in[0];
    const float* x  = (const float*)d_in[1];
    const float* mu = (const float*)d_in[2];
    const float* lv = (const float*)d_in[3];
    const float* nz = (const float*)d_in[4];
    float* ws  = (float*)d_ws;
    float* out = (float*)d_out;

    k_recon <<<2048, 256, 0, stream>>>((const float4*)rx, (const float4*)x, ws);
    k_prep  <<<256, 256, 0, stream>>>(mu, lv, nz, ws);
    k_rowred<<<256, 256, 0, stream>>>(lv, nz, ws);
    k_srow  <<<512, 256, 0, stream>>>(mu, ws);
    k_lqz   <<<4, 256, 0, stream>>>(ws);
    k_sed   <<<dim3(128, 4), 256, 0, stream>>>(mu, ws);
    k_lpr   <<<256, 256, 0, stream>>>(mu, ws);
    k_final <<<1, 256, 0, stream>>>(ws, out);
}

// Round 2
// 47.441 us; speedup vs baseline: 2.0184x; 2.0184x over previous
//
#include <hip/hip_runtime.h>
#include <math.h>

typedef __attribute__((ext_vector_type(8))) short short8;
typedef __attribute__((ext_vector_type(4))) float f32x4;

#define BB 1024
#define DD 64
#define NPIX (1024*3*64*64)

#define LN2PI_F  1.8378770664093453f   // ln(2*pi)
#define LOG2E_F  1.4426950408889634f

#define INV_M  (1.0f/1023.0f)
#define INV_N  (1.0f/50000.0f)
#define STRATF ((float)((50000.0-1023.0)/(50000.0*1023.0)))
#define NEGBIG (-3.0e38f)

// log2 importance weights
#define L2_INVM  (-9.9985904f)    // -log2(1023)
#define L2_INVN  (-15.6096405f)   // -log2(50000)
#define L2_STRAT (-10.0284195f)   // log2(STRATF)

// ws layout (float offsets)
#define WS_RP    0         // 2048
#define WS_LQC   2048      // 1024
#define WS_LPZ   3072      // 1024
#define WS_LQZ   4096      // 1024
#define WS_LPR   5120      // 1024
#define WS_Z     6144      // 65536
#define WS_Z2    71680     // 65536
#define WS_A     137216    // 65536  a = wh (log2-premult)
#define WS_B     202752    // 65536  b = -2*wh*mu
#define WS_C     268288    // 65536  c = wh*mu^2 + c02
#define WS_KC    333824    // 1024   K_j = sum_d c
#define WS_QZP   334848    // 32*1024*2 = 65536 row-LSE partials (m,s)
#define WS_SEDP  400384    // 8*1024*64 = 524288
#define WS_ABF   924672    // bf16 A (1024x128 ushort = 65536 floats)
#define WS_BBF   990208    // bf16 B (65536 floats)

__device__ __forceinline__ float fexp2(float x){ return __builtin_amdgcn_exp2f(x); }
__device__ __forceinline__ float flog2(float x){ return __builtin_amdgcn_logf(x); }
__device__ __forceinline__ unsigned short tobf(float f){
    unsigned int u = __float_as_uint(f);
    u = (u + 0x7FFFu + ((u >> 16) & 1u)) >> 16;
    return (unsigned short)u;
}

// ---------------- kernel 1: recon MSE (blocks 0..2047) + prep (blocks 2048..2303) ----
__global__ __launch_bounds__(256) void k_recon_prep(const float4* __restrict__ rx,
                                                    const float4* __restrict__ x,
                                                    const float* __restrict__ mu,
                                                    const float* __restrict__ logvar,
                                                    const float* __restrict__ noise,
                                                    float* __restrict__ ws) {
    int bid = blockIdx.x, t = threadIdx.x;
    if (bid < 2048) {
        int gid = bid * 256 + t;
        const int n4 = NPIX / 4, stride = 2048 * 256;
        float acc = 0.f;
        for (int idx = gid; idx < n4; idx += stride) {
            float4 a = rx[idx], b = x[idx];
            float d0 = a.x - b.x, d1 = a.y - b.y, d2 = a.z - b.z, d3 = a.w - b.w;
            acc = fmaf(d0, d0, acc); acc = fmaf(d1, d1, acc);
            acc = fmaf(d2, d2, acc); acc = fmaf(d3, d3, acc);
        }
        __shared__ float red[256];
        red[t] = acc; __syncthreads();
        for (int o = 128; o > 0; o >>= 1) {
            if (t < o) red[t] += red[t + o];
            __syncthreads();
        }
        if (t == 0) ws[WS_RP + bid] = red[0];
    } else {
        int pb = bid - 2048;
        int d = t & 63, w = t >> 6;
        int i = pb * 4 + w;
        int idx = i * 64 + d;
        float m = mu[idx], lvv = logvar[idx], n = noise[idx];
        float sh   = fexp2(0.5f * LOG2E_F * lvv);        // e^{lv/2}
        float z    = fmaf(n, sh, m);
        float eneg = fexp2(-LOG2E_F * lvv);              // e^{-lv}
        float a = -0.5f * LOG2E_F * eneg;                // wh (log2 units)
        float b = -2.0f * a * m;
        float c = fmaf(a, m * m, -0.5f * LOG2E_F * (LN2PI_F + lvv));
        float z2 = z * z;
        ws[WS_Z  + idx] = z;  ws[WS_Z2 + idx] = z2;
        ws[WS_A  + idx] = a;  ws[WS_B  + idx] = b;  ws[WS_C + idx] = c;
        unsigned short* abf = (unsigned short*)(ws + WS_ABF);
        unsigned short* bbf = (unsigned short*)(ws + WS_BBF);
        abf[i * 128 + d]      = tobf(z2);
        abf[i * 128 + 64 + d] = tobf(z);
        bbf[i * 128 + d]      = tobf(a);
        bbf[i * 128 + 64 + d] = tobf(b);
        float lqc = -0.5f * (LN2PI_F + lvv + n * n);     // nat
        float lpz = -0.5f * (LN2PI_F + z2);              // nat
        float kc  = c;
        for (int off = 32; off > 0; off >>= 1) {
            lqc += __shfl_xor(lqc, off, 64);
            lpz += __shfl_xor(lpz, off, 64);
            kc  += __shfl_xor(kc,  off, 64);
        }
        if (d == 0) { ws[WS_LQC + i] = lqc; ws[WS_LPZ + i] = lpz; ws[WS_KC + i] = kc; }
    }
}

// ---------------- kernel 2: MFMA S-matrix + row-LSE (blocks 0..255)  ----------------
//                  + per-(i,d) sum over j (blocks 256..1279)
__global__ __launch_bounds__(256) void k_pair(float* __restrict__ ws) {
    __shared__ char smem[32768];
    int bid = blockIdx.x, t = threadIdx.x;
    int lane = t & 63, w = t >> 6;
    if (bid < 256) {
        // ---- 64x64 output tile, K=128 bf16 MFMA ----
        unsigned short* As = (unsigned short*)smem;
        unsigned short* Bs = As + 64 * 128;
        const unsigned short* abf = (const unsigned short*)(ws + WS_ABF);
        const unsigned short* bbf = (const unsigned short*)(ws + WS_BBF);
        int i0 = (bid & 15) * 64, j0 = (bid >> 4) * 64;
        for (int e = 0; e < 4; e++) {
            int lin = e * 256 + t, row = lin >> 4, cu = lin & 15, su = cu ^ (row & 7);
            *(float4*)&As[row * 128 + su * 8] = *(const float4*)&abf[(i0 + row) * 128 + cu * 8];
            *(float4*)&Bs[row * 128 + su * 8] = *(const float4*)&bbf[(j0 + row) * 128 + cu * 8];
        }
        __syncthreads();
        int lo = lane & 15, g = lane >> 4;
        int wi = (w >> 1) * 32, wj = (w & 1) * 32;
        f32x4 acc[2][2] = {};
        for (int kk = 0; kk < 4; kk++) {
            short8 af[2], bfr[2];
            #pragma unroll
            for (int fy = 0; fy < 2; fy++) {
                int rA = wi + fy * 16 + lo;
                int cA = (kk * 4 + g) ^ (rA & 7);
                af[fy] = *(const short8*)&As[rA * 128 + cA * 8];
            }
            #pragma unroll
            for (int fx = 0; fx < 2; fx++) {
                int rB = wj + fx * 16 + lo;
                int cB = (kk * 4 + g) ^ (rB & 7);
                bfr[fx] = *(const short8*)&Bs[rB * 128 + cB * 8];
            }
            #pragma unroll
            for (int fy = 0; fy < 2; fy++)
                #pragma unroll
                for (int fx = 0; fx < 2; fx++)
                    acc[fy][fx] = __builtin_amdgcn_mfma_f32_16x16x32_bf16(af[fy], bfr[fx], acc[fy][fx], 0, 0, 0);
        }
        // epilogue: + K_j + 64*log2(W_ij), online LSE over this wave's 32 j's
        int jA = j0 + wj + lo;
        float kcv0 = ws[WS_KC + jA], kcv1 = ws[WS_KC + jA + 16];
        int pc = (j0 >> 5) + (w & 1);       // 32-wide j-chunk index, 0..31
        #pragma unroll
        for (int fy = 0; fy < 2; fy++) {
            #pragma unroll
            for (int r = 0; r < 4; r++) {
                int i = i0 + wi + fy * 16 + g * 4 + r;
                float vv0, vv1;
                {
                    int j = jA;
                    float lw = (j == 1) ? L2_STRAT : (i == j) ? L2_INVN
                             : (i == 1022 && j == 0) ? L2_STRAT : L2_INVM;
                    vv0 = acc[fy][0][r] + kcv0 + 64.0f * lw;
                }
                {
                    int j = jA + 16;
                    float lw = (j == 1) ? L2_STRAT : (i == j) ? L2_INVN
                             : (i == 1022 && j == 0) ? L2_STRAT : L2_INVM;
                    vv1 = acc[fy][1][r] + kcv1 + 64.0f * lw;
                }
                float m = fmaxf(vv0, vv1);
                float s = fexp2(vv0 - m) + fexp2(vv1 - m);
                for (int off = 1; off < 16; off <<= 1) {
                    float om = __shfl_xor(m, off, 64);
                    float os = __shfl_xor(s, off, 64);
                    float M = fmaxf(m, om);
                    s = s * fexp2(m - M) + os * fexp2(om - M);
                    m = M;
                }
                if (lo == 0) {
                    ws[WS_QZP + ((pc << 10) + i) * 2]     = m;
                    ws[WS_QZP + ((pc << 10) + i) * 2 + 1] = s;
                }
            }
        }
    } else {
        // ---- sed: per-(i,d) unweighted sum_j exp2(u) ----
        float* sacc = (float*)smem;
        int sid = bid - 256;
        int ic = sid & 127, jc = sid >> 7;
        int i0 = ic * 8, d = lane;
        int jbase = jc * 128 + w * 32;
        float z2r[8], zr[8], se[8];
        #pragma unroll
        for (int k = 0; k < 8; k++) {
            z2r[k] = ws[WS_Z2 + (i0 + k) * 64 + d];
            zr[k]  = ws[WS_Z  + (i0 + k) * 64 + d];
            se[k] = 0.f;
        }
        #pragma unroll 2
        for (int jj = 0; jj < 32; jj++) {
            int gidx = (jbase + jj) * 64 + d;
            float av = ws[WS_A + gidx], bv = ws[WS_B + gidx], cv = ws[WS_C + gidx];
            #pragma unroll
            for (int k = 0; k < 8; k++) {
                float u = fmaf(av, z2r[k], fmaf(bv, zr[k], cv));
                se[k] += fexp2(u);
            }
        }
        #pragma unroll
        for (int k = 0; k < 8; k++) sacc[w * 512 + k * 64 + d] = se[k];
        __syncthreads();
        int k0 = w * 2;
        for (int k = k0; k < k0 + 2; k++) {
            float tot = sacc[k * 64 + d] + sacc[512 + k * 64 + d]
                      + sacc[1024 + k * 64 + d] + sacc[1536 + k * 64 + d];
            ws[WS_SEDP + ((jc << 10) + i0 + k) * 64 + d] = tot;
        }
    }
}

// ---------------- kernel 3: combine -> log_qz, log_prod_qzi ----------------
__global__ __launch_bounds__(256) void k_post(float* __restrict__ ws) {
    int t = threadIdx.x, lane = t & 63, w = t >> 6;
    int i = blockIdx.x * 4 + w;
    // log_qz: combine 32 (m,s) chunk partials
    float m = NEGBIG, s = 0.f;
    if (lane < 32) {
        m = ws[WS_QZP + ((lane << 10) + i) * 2];
        s = ws[WS_QZP + ((lane << 10) + i) * 2 + 1];
    }
    for (int off = 1; off < 64; off <<= 1) {
        float om = __shfl_xor(m, off, 64);
        float os = __shfl_xor(s, off, 64);
        float M = fmaxf(m, om);
        s = s * fexp2(m - M) + os * fexp2(om - M);
        m = M;
    }
    if (lane == 0) ws[WS_LQZ + i] = (m + flog2(s)) * (1.0f / LOG2E_F);
    // log_prod_qzi
    int d = lane;
    float se = 0.f;
    for (int c = 0; c < 8; c++) se += ws[WS_SEDP + ((c << 10) + i) * 64 + d];
    float z2 = ws[WS_Z2 + i * 64 + d], z = ws[WS_Z + i * 64 + d];
    auto E = [&](int j) -> float {
        int gidx = j * 64 + d;
        return fexp2(fmaf(ws[WS_A + gidx], z2, fmaf(ws[WS_B + gidx], z, ws[WS_C + gidx])));
    };
    float sid = INV_M * se;
    if (i != 1)    sid += (INV_N  - INV_M) * E(i);
    sid += (STRATF - INV_M) * E(1);
    if (i == 1022) sid += (STRATF - INV_M) * E(0);
    float lg = flog2(sid);
    for (int off = 1; off < 64; off <<= 1) lg += __shfl_xor(lg, off, 64);
    if (d == 0) ws[WS_LPR + i] = lg * (1.0f / LOG2E_F);
}

// ---------------- kernel 4: final combine ----------------
__global__ __launch_bounds__(256) void k_final(const float* __restrict__ ws,
                                               float* __restrict__ out) {
    int t = threadIdx.x;
    float a0 = 0, a1 = 0, a2 = 0, a3 = 0, a4 = 0;
    for (int idx = t; idx < 2048; idx += 256) a0 += ws[WS_RP + idx];
    for (int idx = t; idx < BB; idx += 256) {
        a1 += ws[WS_LQC + idx];
        a2 += ws[WS_LPZ + idx];
        a3 += ws[WS_LQZ + idx];
        a4 += ws[WS_LPR + idx];
    }
    __shared__ float red[256];
    float vals[5] = {a0, a1, a2, a3, a4};
    float res[5];
    for (int q = 0; q < 5; q++) {
        red[t] = vals[q]; __syncthreads();
        for (int o = 128; o > 0; o >>= 1) {
            if (t < o) red[t] += red[t + o];
            __syncthreads();
        }
        res[q] = red[0]; __syncthreads();
    }
    if (t == 0) {
        float recon = res[0], slqc = res[1], slpz = res[2], slqz = res[3], slpr = res[4];
        out[0] = recon + (slqc + 5.f * (slqz - slpr) - slpz) * (1.0f / (float)BB);
    }
}

extern "C" void kernel_launch(void* const* d_in, const int* in_sizes, int n_in,
                              void* d_out, int out_size, void* d_ws, size_t ws_size,
                              hipStream_t stream) {
    (void)in_sizes; (void)n_in; (void)out_size; (void)ws_size;
    const float* rx = (const float*)d_in[0];
    const float* x  = (const float*)d_in[1];
    const float* mu = (const float*)d_in[2];
    const float* lv = (const float*)d_in[3];
    const float* nz = (const float*)d_in[4];
    float* ws  = (float*)d_ws;
    float* out = (float*)d_out;

    k_recon_prep<<<2304, 256, 0, stream>>>((const float4*)rx, (const float4*)x, mu, lv, nz, ws);
    k_pair      <<<1280, 256, 0, stream>>>(ws);
    k_post      <<<256,  256, 0, stream>>>(ws);
    k_final     <<<1,    256, 0, stream>>>(ws, out);
}